// Round 12
// baseline (39.251 us; speedup 1.0000x reference)
//
#include <hip/hip_runtime.h>

// LSTM B=65536, T=9, I=57, H=2 (4H=8) — single-kernel, WAVE-PRIVATE, ZERO-BARRIER.
//
// R8-R11 post-mortem: __syncthreads per chunk forces s_waitcnt vmcnt(0)
// (barrier drain) -> every chunk pays ~full HBM-cold latency. R11 (2x barriers)
// regressed, confirming. Fix: 144 rows/wave = exactly 16 batches x 9 steps ->
// each wave stages its own x region through a wave-private LDS dbuf, writes its
// own gxp segment, and runs the recurrence for its own 16 batches. Producer ==
// consumer wave => NO barriers anywhere; compiler emits counted vmcnt/lgkmcnt
// waits only. Pipeline COMPUTE(c) / WRITE(c+1) / LOAD(c+2) hides HBM latency.
// LDS 35,328 B -> 4 blocks/CU (16 waves/CU).
// DPP rotate-reduce kept (row_ror:N = dst[i]=src[(i-N)&15], proven R9/R10).

#define B_TOTAL 65536
#define T_STEPS 9
#define I_DIM   57
#define BATCH_PER_BLOCK 64
#define ROWS_PER_BLOCK (BATCH_PER_BLOCK * T_STEPS)   // 576
#define ROWS_PER_WAVE  (ROWS_PER_BLOCK / 4)          // 144 = 16 batches x 9
#define WCHUNK_ROWS 8
#define N_WCHUNKS   (ROWS_PER_WAVE / WCHUNK_ROWS)    // 18
#define WCHUNK_DW   (WCHUNK_ROWS * I_DIM)            // 456 dwords, 1824 B
#define WCHUNK_F4   (WCHUNK_DW / 4)                  // 114
#define GX_PAD      9                                 // 8 gates + 1 pad
#define NBLOCKS     (B_TOTAL / BATCH_PER_BLOCK)      // 1024

__device__ __forceinline__ float fast_tanh(float v) {
    // tanh(v) = 1 - 2/(exp(2v)+1); exp(2v) = exp2(2*log2e*v). Err ~1e-6.
    float e = __builtin_amdgcn_exp2f(2.885390082f * v);
    return 1.0f - 2.0f * __builtin_amdgcn_rcpf(e + 1.0f);
}
__device__ __forceinline__ float fast_sig(float v) {
    return 0.5f * fast_tanh(0.5f * v) + 0.5f;
}

// row_ror:N within 16-lane DPP rows; CTRL = 0x120 | N (compile-time const).
// Semantics (established by R9 fail / R10 pass): dst[i] = src[(i-N)&15].
#define DPP_ROR_F32(VAR, SRC, CTRL)                                          \
    float VAR = __builtin_bit_cast(float, __builtin_amdgcn_update_dpp(       \
        0, __builtin_bit_cast(int, SRC), (CTRL), 0xF, 0xF, false))

__global__ __launch_bounds__(256, 4)
void lstm_onepass(const float* __restrict__ x,
                  const float* __restrict__ W_ih,
                  const float* __restrict__ W_hh,
                  const float* __restrict__ b_ih,
                  const float* __restrict__ b_hh,
                  const float* __restrict__ fc_w,
                  const float* __restrict__ fc_b,
                  float* __restrict__ out) {
    // Wave-private staging dbuf + block gxp (wave-disjoint segments).
    __shared__ float xs[4][2][WCHUNK_DW];             // 14592 B
    __shared__ float gxp[ROWS_PER_BLOCK * GX_PAD];    // 20736 B  (total 35328)

    const int tid  = threadIdx.x;
    const int wv   = tid >> 6;          // wave 0..3 (owns batches wv*16..+15)
    const int lane = tid & 63;
    const int cl   = (lane >> 4) & 3;   // 16-lane cluster (DPP row) 0..3
    const int g    = (lane >> 1) & 7;   // gate lane 0..7
    const int p    = lane & 1;          // row parity within cluster
    const int rin  = cl * 2 + p;        // row-in-chunk 0..7

    // Rotated weight slices: acc[d] accumulates gate (g+d)&7 over slice {g+8k}.
    // wrot[d][7] pairs with broadcast x[56]; only g==0 lane contributes.
    float wrot[8][8];
#pragma unroll
    for (int d = 0; d < 8; ++d) {
        const int gg = (g + d) & 7;
        const float* wr = W_ih + gg * I_DIM;
#pragma unroll
        for (int k = 0; k < 7; ++k) wrot[d][k] = wr[g + 8 * k];
        wrot[d][7] = (g == 0) ? wr[56] : 0.0f;
    }
    float bsum = b_ih[g] + b_hh[g];
#pragma unroll
    for (int d = 0; d < 8; ++d)
#pragma unroll
        for (int k = 0; k < 8; ++k)
            asm volatile("" : "+v"(wrot[d][k]));

    // Wave's x region: 144 rows contiguous, 16B-aligned (144*228 = 32832 B).
    const float* xw = x + (size_t)blockIdx.x * (ROWS_PER_BLOCK * I_DIM)
                        + (size_t)wv * (ROWS_PER_WAVE * I_DIM);

    float4 st0, st1;

#define STAGE_LOAD(C) do {                                                  \
        const float4* xc_ = (const float4*)(xw + (size_t)(C) * WCHUNK_DW);  \
        st0 = xc_[lane];                                                    \
        if (lane < WCHUNK_F4 - 64) st1 = xc_[64 + lane];                    \
    } while (0)

#define STAGE_WRITE(S) do {                                                 \
        float4* L_ = (float4*)xs[wv][S];                                    \
        L_[lane] = st0;                                                     \
        if (lane < WCHUNK_F4 - 64) L_[64 + lane] = st1;                     \
    } while (0)

    // Compute 1 row per thread (row rin of chunk C) from wave buffer S.
#define COMPUTE(S, C) do {                                                  \
        const float* row_ = xs[wv][S] + rin * I_DIM;                        \
        float xv_[8];                                                       \
        _Pragma("unroll")                                                   \
        for (int k = 0; k < 7; ++k) xv_[k] = row_[g + 8 * k];               \
        xv_[7] = row_[56];   /* broadcast; pairs with wrot[d][7] */         \
        float acc_[8];                                                      \
        _Pragma("unroll")                                                   \
        for (int d = 0; d < 8; ++d) {                                       \
            float s_ = wrot[d][0] * xv_[0];                                 \
            _Pragma("unroll")                                               \
            for (int k = 1; k < 8; ++k) s_ += wrot[d][k] * xv_[k];          \
            acc_[d] = s_;                                                   \
        }                                                                   \
        /* DPP rotate-gather: gate g takes acc[d] from gate (g-d)&7,        \
           same parity: row_ror:(2d). Tree add, VALU-only. */               \
        DPP_ROR_F32(r1_, acc_[1], 0x122);                                   \
        DPP_ROR_F32(r2_, acc_[2], 0x124);                                   \
        DPP_ROR_F32(r3_, acc_[3], 0x126);                                   \
        DPP_ROR_F32(r4_, acc_[4], 0x128);                                   \
        DPP_ROR_F32(r5_, acc_[5], 0x12A);                                   \
        DPP_ROR_F32(r6_, acc_[6], 0x12C);                                   \
        DPP_ROR_F32(r7_, acc_[7], 0x12E);                                   \
        float tot_ = ((acc_[0] + r1_) + (r2_ + r3_))                        \
                   + ((r4_ + r5_) + (r6_ + r7_)) + bsum;                    \
        gxp[(wv * ROWS_PER_WAVE + (C) * WCHUNK_ROWS + rin) * GX_PAD + g]    \
            = tot_;                                                         \
    } while (0)

    // Barrier-free software pipeline: loads get a full COMPUTE to land.
    STAGE_LOAD(0);
    STAGE_WRITE(0);
    STAGE_LOAD(1);

#pragma unroll
    for (int cc = 0; cc < N_WCHUNKS; ++cc) {
        COMPUTE(cc & 1, cc);                              // read buf cc
        if (cc + 1 < N_WCHUNKS) STAGE_WRITE((cc + 1) & 1); // st -> buf cc+1
        if (cc + 2 < N_WCHUNKS) STAGE_LOAD(cc + 2);        // refill st
    }
#undef STAGE_LOAD
#undef STAGE_WRITE
#undef COMPUTE

    // ---------------- Phase B: recurrence, wave-private, no barrier --------
    // Wave wv computed gxp rows for batches wv*16..wv*16+15; lanes 0..15 of
    // the same wave consume them. Within-wave LDS ordering = lgkmcnt (auto).
    if (lane < 16) {
        float w0[8], w1[8];
#pragma unroll
        for (int q = 0; q < 8; ++q) {
            w0[q] = W_hh[q * 2];
            w1[q] = W_hh[q * 2 + 1];
        }

        const int bloc = wv * 16 + lane;                   // batch in block
        float h0 = 0.f, h1 = 0.f, c0 = 0.f, c1 = 0.f;
        const float* gb = gxp + bloc * (T_STEPS * GX_PAD); // stride 81 floats
                                                           // (16 lanes x 17 mod 32:
                                                           //  all-distinct banks)

#pragma unroll
        for (int t = 0; t < T_STEPS; ++t) {
            const float* pp = gb + t * GX_PAD;
            // gate rows [i0,i1,f0,f1,g0,g1,o0,o1]
            const float i0 = fast_sig (pp[0] + h0 * w0[0] + h1 * w1[0]);
            const float i1 = fast_sig (pp[1] + h0 * w0[1] + h1 * w1[1]);
            const float f0 = fast_sig (pp[2] + h0 * w0[2] + h1 * w1[2]);
            const float f1 = fast_sig (pp[3] + h0 * w0[3] + h1 * w1[3]);
            const float g0 = fast_tanh(pp[4] + h0 * w0[4] + h1 * w1[4]);
            const float g1 = fast_tanh(pp[5] + h0 * w0[5] + h1 * w1[5]);
            const float o0 = fast_sig (pp[6] + h0 * w0[6] + h1 * w1[6]);
            const float o1 = fast_sig (pp[7] + h0 * w0[7] + h1 * w1[7]);
            c0 = f0 * c0 + i0 * g0;
            c1 = f1 * c1 + i1 * g1;
            h0 = o0 * fast_tanh(c0);
            h1 = o1 * fast_tanh(c1);
        }

        out[blockIdx.x * BATCH_PER_BLOCK + bloc] =
            h0 * fc_w[0] + h1 * fc_w[1] + fc_b[0];
    }
}

extern "C" void kernel_launch(void* const* d_in, const int* in_sizes, int n_in,
                              void* d_out, int out_size, void* d_ws, size_t ws_size,
                              hipStream_t stream) {
    const float* x    = (const float*)d_in[0];
    const float* W_ih = (const float*)d_in[1];
    const float* W_hh = (const float*)d_in[2];
    const float* b_ih = (const float*)d_in[3];
    const float* b_hh = (const float*)d_in[4];
    const float* fc_w = (const float*)d_in[5];
    const float* fc_b = (const float*)d_in[6];
    float* out = (float*)d_out;

    lstm_onepass<<<dim3(NBLOCKS), dim3(256), 0, stream>>>(
        x, W_ih, W_hh, b_ih, b_hh, fc_w, fc_b, out);
}

// Round 13
// 37.646 us; speedup vs baseline: 1.0426x; 1.0426x over previous
//
#include <hip/hip_runtime.h>

// LSTM B=65536, T=9, I=57, H=2 (4H=8) — wave-private, zero-barrier,
// DEPTH-3 prefetch pipeline.
//
// R8-R12 evidence: DPP vs shfl null; 3 vs 4 blocks/CU null; barriers vs none
// null. What correlates: per-chunk in-flight bytes (R8 9x14.6KB = 33.7us beats
// 18-chunk variants = 39us). R12's ds_write(c+1) waited on a load issued only
// ~1 compute phase (~350cy) earlier vs ~900cy cold-HBM latency -> ~500cy stall
// per chunk. Fix: 3 named register slots, LOAD(c+3) issued 3 compute phases
// (~1000cy) before its ds_write -> counted vmcnt already satisfied at wait.
// DPP rotate-reduce kept (row_ror:N = dst[i]=src[(i-N)&15], proven R9/R10).

#define B_TOTAL 65536
#define T_STEPS 9
#define I_DIM   57
#define BATCH_PER_BLOCK 64
#define ROWS_PER_BLOCK (BATCH_PER_BLOCK * T_STEPS)   // 576
#define ROWS_PER_WAVE  (ROWS_PER_BLOCK / 4)          // 144 = 16 batches x 9
#define WCHUNK_ROWS 8
#define N_WCHUNKS   (ROWS_PER_WAVE / WCHUNK_ROWS)    // 18
#define WCHUNK_DW   (WCHUNK_ROWS * I_DIM)            // 456 dwords, 1824 B
#define WCHUNK_F4   (WCHUNK_DW / 4)                  // 114
#define GX_PAD      9                                 // 8 gates + 1 pad
#define NBLOCKS     (B_TOTAL / BATCH_PER_BLOCK)      // 1024

__device__ __forceinline__ float fast_tanh(float v) {
    // tanh(v) = 1 - 2/(exp(2v)+1); exp(2v) = exp2(2*log2e*v). Err ~1e-6.
    float e = __builtin_amdgcn_exp2f(2.885390082f * v);
    return 1.0f - 2.0f * __builtin_amdgcn_rcpf(e + 1.0f);
}
__device__ __forceinline__ float fast_sig(float v) {
    return 0.5f * fast_tanh(0.5f * v) + 0.5f;
}

// row_ror:N within 16-lane DPP rows; CTRL = 0x120 | N (compile-time const).
// Semantics (established by R9 fail / R10 pass): dst[i] = src[(i-N)&15].
#define DPP_ROR_F32(VAR, SRC, CTRL)                                          \
    float VAR = __builtin_bit_cast(float, __builtin_amdgcn_update_dpp(       \
        0, __builtin_bit_cast(int, SRC), (CTRL), 0xF, 0xF, false))

__global__ __launch_bounds__(256, 4)
void lstm_onepass(const float* __restrict__ x,
                  const float* __restrict__ W_ih,
                  const float* __restrict__ W_hh,
                  const float* __restrict__ b_ih,
                  const float* __restrict__ b_hh,
                  const float* __restrict__ fc_w,
                  const float* __restrict__ fc_b,
                  float* __restrict__ out) {
    // Wave-private staging dbuf + block gxp (wave-disjoint segments).
    __shared__ float xs[4][2][WCHUNK_DW];             // 14592 B
    __shared__ float gxp[ROWS_PER_BLOCK * GX_PAD];    // 20736 B  (total 35328
                                                      //  -> 4 blocks/CU)

    const int tid  = threadIdx.x;
    const int wv   = tid >> 6;          // wave 0..3 (owns batches wv*16..+15)
    const int lane = tid & 63;
    const int cl   = (lane >> 4) & 3;   // 16-lane cluster (DPP row) 0..3
    const int g    = (lane >> 1) & 7;   // gate lane 0..7
    const int p    = lane & 1;          // row parity within cluster
    const int rin  = cl * 2 + p;        // row-in-chunk 0..7

    // Rotated weight slices over i=0..55: wrot[d][k] = W[(g+d)&7][g+8k].
    // x[56] handled separately: + w56 * x56 after the rotate-reduce.
    float wrot[8][7];
#pragma unroll
    for (int d = 0; d < 8; ++d) {
        const int gg = (g + d) & 7;
        const float* wr = W_ih + gg * I_DIM;
#pragma unroll
        for (int k = 0; k < 7; ++k) wrot[d][k] = wr[g + 8 * k];
    }
    float w56  = W_ih[g * I_DIM + 56];
    float bsum = b_ih[g] + b_hh[g];
#pragma unroll
    for (int d = 0; d < 8; ++d)
#pragma unroll
        for (int k = 0; k < 7; ++k)
            asm volatile("" : "+v"(wrot[d][k]));
    asm volatile("" : "+v"(w56), "+v"(bsum));

    // Wave's x region: 144 rows contiguous, 16B-aligned (144*228 = 32832 B).
    const float* xw = x + (size_t)blockIdx.x * (ROWS_PER_BLOCK * I_DIM)
                        + (size_t)wv * (ROWS_PER_WAVE * I_DIM);

    // Three named prefetch slots (static names — rule #20). Chunk c -> slot c%3.
    float4 s0a, s0b, s1a, s1b, s2a, s2b;

#define SLOAD(C, RA, RB) do {                                               \
        const float4* xc_ = (const float4*)(xw + (size_t)(C) * WCHUNK_DW);  \
        RA = xc_[lane];                                                     \
        if (lane < WCHUNK_F4 - 64) RB = xc_[64 + lane];                     \
    } while (0)

#define SWRITE(S, RA, RB) do {                                              \
        float4* L_ = (float4*)xs[wv][S];                                    \
        L_[lane] = RA;                                                      \
        if (lane < WCHUNK_F4 - 64) L_[64 + lane] = RB;                      \
    } while (0)

    // Compute 1 row per thread (row rin of chunk C) from wave buffer S.
#define COMPUTE(S, C) do {                                                  \
        const float* row_ = xs[wv][S] + rin * I_DIM;                        \
        float xv_[7];                                                       \
        _Pragma("unroll")                                                   \
        for (int k = 0; k < 7; ++k) xv_[k] = row_[g + 8 * k];               \
        const float x56_ = row_[56];   /* broadcast across group */         \
        float acc_[8];                                                      \
        _Pragma("unroll")                                                   \
        for (int d = 0; d < 8; ++d) {                                       \
            float s_ = wrot[d][0] * xv_[0];                                 \
            _Pragma("unroll")                                               \
            for (int k = 1; k < 7; ++k) s_ += wrot[d][k] * xv_[k];          \
            acc_[d] = s_;                                                   \
        }                                                                   \
        /* DPP rotate-gather: gate g takes acc[d] from gate (g-d)&7,        \
           same parity: row_ror:(2d). Tree add, VALU-only. */               \
        DPP_ROR_F32(r1_, acc_[1], 0x122);                                   \
        DPP_ROR_F32(r2_, acc_[2], 0x124);                                   \
        DPP_ROR_F32(r3_, acc_[3], 0x126);                                   \
        DPP_ROR_F32(r4_, acc_[4], 0x128);                                   \
        DPP_ROR_F32(r5_, acc_[5], 0x12A);                                   \
        DPP_ROR_F32(r6_, acc_[6], 0x12C);                                   \
        DPP_ROR_F32(r7_, acc_[7], 0x12E);                                   \
        float tot_ = ((acc_[0] + r1_) + (r2_ + r3_))                        \
                   + ((r4_ + r5_) + (r6_ + r7_))                            \
                   + bsum + w56 * x56_;                                     \
        gxp[(wv * ROWS_PER_WAVE + (C) * WCHUNK_ROWS + rin) * GX_PAD + g]    \
            = tot_;                                                         \
    } while (0)

    // Prologue: fill the 3-deep pipeline, commit chunk 0 to LDS.
    SLOAD(0, s0a, s0b);
    SLOAD(1, s1a, s1b);
    SLOAD(2, s2a, s2b);
    SWRITE(0, s0a, s0b);

#pragma unroll
    for (int cc = 0; cc < N_WCHUNKS; ++cc) {
        COMPUTE(cc & 1, cc);
        // Refill slot cc%3 with chunk cc+3 (slot's old chunk cc already in LDS).
        if (cc + 3 < N_WCHUNKS) {
            if      (cc % 3 == 0) SLOAD(cc + 3, s0a, s0b);
            else if (cc % 3 == 1) SLOAD(cc + 3, s1a, s1b);
            else                  SLOAD(cc + 3, s2a, s2b);
        }
        // Commit chunk cc+1 (loaded 3 compute phases ago) to the other buffer.
        if (cc + 1 < N_WCHUNKS) {
            if      ((cc + 1) % 3 == 0) SWRITE((cc + 1) & 1, s0a, s0b);
            else if ((cc + 1) % 3 == 1) SWRITE((cc + 1) & 1, s1a, s1b);
            else                        SWRITE((cc + 1) & 1, s2a, s2b);
        }
    }
#undef SLOAD
#undef SWRITE
#undef COMPUTE

    // ---------------- Phase B: recurrence, wave-private, no barrier --------
    // Wave wv computed gxp rows for batches wv*16..wv*16+15; lanes 0..15 of
    // the same wave consume them. Within-wave LDS ordering = lgkmcnt (auto).
    if (lane < 16) {
        float w0[8], w1[8];
#pragma unroll
        for (int q = 0; q < 8; ++q) {
            w0[q] = W_hh[q * 2];
            w1[q] = W_hh[q * 2 + 1];
        }

        const int bloc = wv * 16 + lane;                   // batch in block
        float h0 = 0.f, h1 = 0.f, c0 = 0.f, c1 = 0.f;
        const float* gb = gxp + bloc * (T_STEPS * GX_PAD); // stride 81 floats

#pragma unroll
        for (int t = 0; t < T_STEPS; ++t) {
            const float* pp = gb + t * GX_PAD;
            // gate rows [i0,i1,f0,f1,g0,g1,o0,o1]
            const float i0 = fast_sig (pp[0] + h0 * w0[0] + h1 * w1[0]);
            const float i1 = fast_sig (pp[1] + h0 * w0[1] + h1 * w1[1]);
            const float f0 = fast_sig (pp[2] + h0 * w0[2] + h1 * w1[2]);
            const float f1 = fast_sig (pp[3] + h0 * w0[3] + h1 * w1[3]);
            const float g0 = fast_tanh(pp[4] + h0 * w0[4] + h1 * w1[4]);
            const float g1 = fast_tanh(pp[5] + h0 * w0[5] + h1 * w1[5]);
            const float o0 = fast_sig (pp[6] + h0 * w0[6] + h1 * w1[6]);
            const float o1 = fast_sig (pp[7] + h0 * w0[7] + h1 * w1[7]);
            c0 = f0 * c0 + i0 * g0;
            c1 = f1 * c1 + i1 * g1;
            h0 = o0 * fast_tanh(c0);
            h1 = o1 * fast_tanh(c1);
        }

        out[blockIdx.x * BATCH_PER_BLOCK + bloc] =
            h0 * fc_w[0] + h1 * fc_w[1] + fc_b[0];
    }
}

extern "C" void kernel_launch(void* const* d_in, const int* in_sizes, int n_in,
                              void* d_out, int out_size, void* d_ws, size_t ws_size,
                              hipStream_t stream) {
    const float* x    = (const float*)d_in[0];
    const float* W_ih = (const float*)d_in[1];
    const float* W_hh = (const float*)d_in[2];
    const float* b_ih = (const float*)d_in[3];
    const float* b_hh = (const float*)d_in[4];
    const float* fc_w = (const float*)d_in[5];
    const float* fc_b = (const float*)d_in[6];
    float* out = (float*)d_out;

    lstm_onepass<<<dim3(NBLOCKS), dim3(256), 0, stream>>>(
        x, W_ih, W_hh, b_ih, b_hh, fc_w, fc_b, out);
}